// Round 1
// baseline (3146.650 us; speedup 1.0000x reference)
//
#include <hip/hip_runtime.h>
#include <hip/hip_bf16.h>
#include <math.h>

#define NPC   2048          // points per cloud
#define NC    8             // clouds
#define NTOT  (NPC * NC)    // 16384
#define KMAX  32
#define R2    0.04f         // f32(0.04) — boundary-exact vs numpy's f64 compare

// ---------------- neighbor search: one wave per query ----------------
__global__ __launch_bounds__(256) void nbr_kernel(const float* __restrict__ pos,
                                                  int* __restrict__ nbr,
                                                  int* __restrict__ cnts) {
    int gid  = blockIdx.x * 256 + threadIdx.x;
    int q    = gid >> 6;                 // global query index
    int lane = threadIdx.x & 63;
    int base = (q >> 11) << 11;          // cloud start row
    float qx = pos[3*q], qy = pos[3*q+1], qz = pos[3*q+2];
    int cnt = 0;
    for (int j0 = 0; j0 < NPC && cnt < KMAX; j0 += 64) {
        int j = base + j0 + lane;
        // block FMA contraction: must match numpy's rounding exactly
        float dx = __fsub_rn(pos[3*j],   qx);
        float dy = __fsub_rn(pos[3*j+1], qy);
        float dz = __fsub_rn(pos[3*j+2], qz);
        float d2 = __fadd_rn(__fadd_rn(__fmul_rn(dx,dx), __fmul_rn(dy,dy)),
                             __fmul_rn(dz,dz));
        bool val = d2 <= R2;
        unsigned long long m = __ballot(val);
        int before = (int)__popcll(m & ((1ull << lane) - 1ull));
        int slot = cnt + before;
        if (val && slot < KMAX) nbr[(q << 5) + slot] = j;   // ascending index order
        cnt += (int)__popcll(m);
    }
    if (lane == 0) cnts[q] = cnt < KMAX ? cnt : KMAX;
}

// ---------------- fused MLP + max-aggregation: one thread per (query, slot) ----------------
__device__ __forceinline__ float4 ld4(const float* p) {
    return *reinterpret_cast<const float4*>(p);
}

__global__ __launch_bounds__(256) void mlp_kernel(
    const float* __restrict__ x, const float* __restrict__ pos,
    const float* __restrict__ W1, const float* __restrict__ b1,
    const float* __restrict__ W2, const float* __restrict__ b2,
    const float* __restrict__ W3, const float* __restrict__ b3,
    const int* __restrict__ nbr, const int* __restrict__ cnts,
    float* __restrict__ out)
{
    int r = blockIdx.x * 256 + threadIdx.x;  // edge row
    int q = r >> 5;                          // query
    int k = r & 31;                          // neighbor slot
    int cnt = cnts[q];
    bool valid = k < cnt;
    int jg = valid ? nbr[(q << 5) + k] : q;  // safe in-bounds gather for invalid slots

    float msg[6];
    msg[0] = x[3*jg]; msg[1] = x[3*jg+1]; msg[2] = x[3*jg+2];
    msg[3] = pos[3*jg]   - pos[3*q];
    msg[4] = pos[3*jg+1] - pos[3*q+1];
    msg[5] = pos[3*jg+2] - pos[3*q+2];

    // ---- layer 1: 6 -> 64, relu ----
    float h1v[64];
    #pragma unroll
    for (int o = 0; o < 64; o += 4) {
        float4 a = ld4(b1 + o);
        float a0=a.x, a1=a.y, a2=a.z, a3=a.w;
        #pragma unroll
        for (int c = 0; c < 6; ++c) {
            float4 w = ld4(W1 + c*64 + o);
            a0 = fmaf(msg[c], w.x, a0);
            a1 = fmaf(msg[c], w.y, a1);
            a2 = fmaf(msg[c], w.z, a2);
            a3 = fmaf(msg[c], w.w, a3);
        }
        h1v[o]   = fmaxf(a0, 0.f);
        h1v[o+1] = fmaxf(a1, 0.f);
        h1v[o+2] = fmaxf(a2, 0.f);
        h1v[o+3] = fmaxf(a3, 0.f);
    }

    // ---- layer 2: 64 -> 64, relu ----
    float h2v[64];
    #pragma unroll
    for (int o = 0; o < 64; o += 4) {
        float4 a = ld4(b2 + o);
        h2v[o] = a.x; h2v[o+1] = a.y; h2v[o+2] = a.z; h2v[o+3] = a.w;
    }
    #pragma unroll
    for (int c = 0; c < 64; ++c) {
        float hc = h1v[c];
        #pragma unroll
        for (int o = 0; o < 64; o += 4) {
            float4 w = ld4(W2 + c*64 + o);
            h2v[o]   = fmaf(hc, w.x, h2v[o]);
            h2v[o+1] = fmaf(hc, w.y, h2v[o+1]);
            h2v[o+2] = fmaf(hc, w.z, h2v[o+2]);
            h2v[o+3] = fmaf(hc, w.w, h2v[o+3]);
        }
    }
    #pragma unroll
    for (int o = 0; o < 64; ++o) h2v[o] = fmaxf(h2v[o], 0.f);

    // ---- layer 3: 64 -> 128 in 4 chunks of 32, then max-reduce over 32 lanes ----
    #pragma unroll 1
    for (int ch = 0; ch < 4; ++ch) {
        float acc[32];
        #pragma unroll
        for (int m = 0; m < 32; m += 4) {
            float4 a = ld4(b3 + ch*32 + m);
            acc[m] = a.x; acc[m+1] = a.y; acc[m+2] = a.z; acc[m+3] = a.w;
        }
        #pragma unroll
        for (int c = 0; c < 64; ++c) {
            float hc = h2v[c];
            #pragma unroll
            for (int m = 0; m < 32; m += 4) {
                float4 w = ld4(W3 + c*128 + ch*32 + m);
                acc[m]   = fmaf(hc, w.x, acc[m]);
                acc[m+1] = fmaf(hc, w.y, acc[m+1]);
                acc[m+2] = fmaf(hc, w.z, acc[m+2]);
                acc[m+3] = fmaf(hc, w.w, acc[m+3]);
            }
        }
        #pragma unroll
        for (int m = 0; m < 32; ++m) {
            float v = valid ? acc[m] : -INFINITY;
            v = fmaxf(v, __shfl_xor(v, 16));
            v = fmaxf(v, __shfl_xor(v, 8));
            v = fmaxf(v, __shfl_xor(v, 4));
            v = fmaxf(v, __shfl_xor(v, 2));
            v = fmaxf(v, __shfl_xor(v, 1));
            if (k == 0) out[q*128 + ch*32 + m] = v;
        }
    }
}

// ---------------- tail: copy pos + batch into output tuple ----------------
__global__ void tail_kernel(const float* __restrict__ pos,
                            const int* __restrict__ batch,
                            float* __restrict__ out) {
    int i = blockIdx.x * 256 + threadIdx.x;
    if (i < NTOT*3) out[NTOT*128 + i] = pos[i];
    if (i < NTOT)   out[NTOT*131 + i] = (float)batch[i];
}

extern "C" void kernel_launch(void* const* d_in, const int* in_sizes, int n_in,
                              void* d_out, int out_size, void* d_ws, size_t ws_size,
                              hipStream_t stream) {
    const float* x     = (const float*)d_in[0];
    const float* pos   = (const float*)d_in[1];
    const int*   batch = (const int*)d_in[2];
    const float* W1    = (const float*)d_in[3];
    const float* b1    = (const float*)d_in[4];
    const float* W2    = (const float*)d_in[5];
    const float* b2    = (const float*)d_in[6];
    const float* W3    = (const float*)d_in[7];
    const float* b3    = (const float*)d_in[8];
    float* out = (float*)d_out;

    int* nbr  = (int*)d_ws;                 // [NTOT][32] global neighbor rows
    int* cnts = nbr + NTOT * KMAX;          // [NTOT]

    nbr_kernel<<<NTOT * 64 / 256, 256, 0, stream>>>(pos, nbr, cnts);
    mlp_kernel<<<NTOT * KMAX / 256, 256, 0, stream>>>(x, pos, W1, b1, W2, b2, W3, b3,
                                                      nbr, cnts, out);
    tail_kernel<<<(NTOT * 3 + 255) / 256, 256, 0, stream>>>(pos, batch, out);
}

// Round 2
// 118.211 us; speedup vs baseline: 26.6189x; 26.6189x over previous
//
#include <hip/hip_runtime.h>
#include <hip/hip_bf16.h>
#include <math.h>

#define NPC   2048          // points per cloud
#define NC    8             // clouds
#define NTOT  (NPC * NC)    // 16384
#define KMAX  32
#define R2    0.04f         // f32(0.04) — boundary-exact vs numpy's f64 compare
#define PAD   72            // padded row length (bf16 elems): 144B stride -> 2-way bank alias (free)

typedef short bf16x8 __attribute__((ext_vector_type(8)));
typedef float f32x4  __attribute__((ext_vector_type(4)));

__device__ __forceinline__ float4 ld4(const float* p) {
    return *reinterpret_cast<const float4*>(p);
}

// f32 -> bf16 round-to-nearest-even (all values finite here)
__device__ __forceinline__ unsigned int f2bf(float f) {
    unsigned int u = __float_as_uint(f);
    return (u + 0x7FFFu + ((u >> 16) & 1u)) >> 16;
}

// ---------------- neighbor search: one wave per query (unchanged, validated exact) ----------------
__global__ __launch_bounds__(256) void nbr_kernel(const float* __restrict__ pos,
                                                  int* __restrict__ nbr,
                                                  int* __restrict__ cnts) {
    int gid  = blockIdx.x * 256 + threadIdx.x;
    int q    = gid >> 6;
    int lane = threadIdx.x & 63;
    int base = (q >> 11) << 11;
    float qx = pos[3*q], qy = pos[3*q+1], qz = pos[3*q+2];
    int cnt = 0;
    for (int j0 = 0; j0 < NPC && cnt < KMAX; j0 += 64) {
        int j = base + j0 + lane;
        float dx = __fsub_rn(pos[3*j],   qx);
        float dy = __fsub_rn(pos[3*j+1], qy);
        float dz = __fsub_rn(pos[3*j+2], qz);
        float d2 = __fadd_rn(__fadd_rn(__fmul_rn(dx,dx), __fmul_rn(dy,dy)),
                             __fmul_rn(dz,dz));
        bool val = d2 <= R2;
        unsigned long long m = __ballot(val);
        int before = (int)__popcll(m & ((1ull << lane) - 1ull));
        int slot = cnt + before;
        if (val && slot < KMAX) nbr[(q << 5) + slot] = j;
        cnt += (int)__popcll(m);
    }
    if (lane == 0) cnts[q] = cnt < KMAX ? cnt : KMAX;
}

// ---------------- fused MLP (MFMA) + max-aggregation ----------------
// Block: 256 threads = 4 waves; 4 queries = 128 edge-rows. Wave w owns rows [w*32, w*32+32) = query q0+w.
__global__ __launch_bounds__(256, 2) void mlp_kernel(
    const float* __restrict__ x, const float* __restrict__ pos,
    const float* __restrict__ W1, const float* __restrict__ b1,
    const float* __restrict__ W2, const float* __restrict__ b2,
    const float* __restrict__ W3, const float* __restrict__ b3,
    const int* __restrict__ nbr, const int* __restrict__ cnts,
    float* __restrict__ out)
{
    __shared__ unsigned short sH1[128 * PAD];   // h1 tile, bf16       (18432 B)
    __shared__ unsigned short sH2[128 * PAD];   // h2 tile, bf16       (18432 B)
    __shared__ unsigned short sW2T[64 * PAD];   // W2^T [out][in] bf16 ( 9216 B)
    __shared__ unsigned short sW3T[128 * PAD];  // W3^T [out][in] bf16 (18432 B)

    const int tid  = threadIdx.x;
    const int wave = tid >> 6, lane = tid & 63;
    const int l15  = lane & 15, lg = lane >> 4;
    const int q0   = blockIdx.x * 4;

    // --- stage weights as bf16, transposed (once per block) ---
    for (int i = tid; i < 64 * 64; i += 256) {
        int k = i >> 6, n = i & 63;
        sW2T[n * PAD + k] = (unsigned short)f2bf(W2[i]);
    }
    for (int i = tid; i < 64 * 128; i += 256) {
        int k = i >> 7, n = i & 127;
        sW3T[n * PAD + k] = (unsigned short)f2bf(W3[i]);
    }

    // --- layer 1 (VALU): 2 threads per edge, 32 outputs each ---
    {
        int e    = tid >> 1;           // edge row in block (0..127)
        int half = tid & 1;
        int q    = q0 + (e >> 5);
        int k    = e & 31;
        int cnt  = cnts[q];
        int jg   = (k < cnt) ? nbr[(q << 5) + k] : q;

        float msg[6];
        msg[0] = x[3*jg]; msg[1] = x[3*jg+1]; msg[2] = x[3*jg+2];
        msg[3] = pos[3*jg]   - pos[3*q];
        msg[4] = pos[3*jg+1] - pos[3*q+1];
        msg[5] = pos[3*jg+2] - pos[3*q+2];

        float hv[32];
        #pragma unroll
        for (int o = 0; o < 32; o += 4) {
            float4 bb = ld4(b1 + half * 32 + o);
            float a0 = bb.x, a1 = bb.y, a2 = bb.z, a3 = bb.w;
            #pragma unroll
            for (int c = 0; c < 6; ++c) {
                float4 w = ld4(W1 + c * 64 + half * 32 + o);
                a0 = fmaf(msg[c], w.x, a0);
                a1 = fmaf(msg[c], w.y, a1);
                a2 = fmaf(msg[c], w.z, a2);
                a3 = fmaf(msg[c], w.w, a3);
            }
            hv[o]   = fmaxf(a0, 0.f);
            hv[o+1] = fmaxf(a1, 0.f);
            hv[o+2] = fmaxf(a2, 0.f);
            hv[o+3] = fmaxf(a3, 0.f);
        }
        int4* dst = (int4*)&sH1[e * PAD + half * 32];
        #pragma unroll
        for (int g = 0; g < 4; ++g) {
            int4 v;
            v.x = (int)(f2bf(hv[g*8+0]) | (f2bf(hv[g*8+1]) << 16));
            v.y = (int)(f2bf(hv[g*8+2]) | (f2bf(hv[g*8+3]) << 16));
            v.z = (int)(f2bf(hv[g*8+4]) | (f2bf(hv[g*8+5]) << 16));
            v.w = (int)(f2bf(hv[g*8+6]) | (f2bf(hv[g*8+7]) << 16));
            dst[g] = v;
        }
    }
    __syncthreads();

    const int row0 = wave * 32;

    // --- GEMM2: H2 = relu(H1 @ W2 + b2), per wave 32x64, K=64 ---
    {
        bf16x8 a2[2][2];
        #pragma unroll
        for (int m = 0; m < 2; ++m)
            #pragma unroll
            for (int s = 0; s < 2; ++s)
                a2[m][s] = *(const bf16x8*)&sH1[(row0 + m*16 + l15) * PAD + s*32 + lg*8];

        f32x4 acc2[2][4] = {};
        #pragma unroll
        for (int n = 0; n < 4; ++n) {
            bf16x8 b0 = *(const bf16x8*)&sW2T[(n*16 + l15) * PAD +      lg*8];
            bf16x8 b1f= *(const bf16x8*)&sW2T[(n*16 + l15) * PAD + 32 + lg*8];
            #pragma unroll
            for (int m = 0; m < 2; ++m) {
                acc2[m][n] = __builtin_amdgcn_mfma_f32_16x16x32_bf16(a2[m][0], b0,  acc2[m][n], 0, 0, 0);
                acc2[m][n] = __builtin_amdgcn_mfma_f32_16x16x32_bf16(a2[m][1], b1f, acc2[m][n], 0, 0, 0);
            }
        }
        #pragma unroll
        for (int n = 0; n < 4; ++n) {
            float bias = b2[n*16 + l15];
            #pragma unroll
            for (int m = 0; m < 2; ++m) {
                #pragma unroll
                for (int i = 0; i < 4; ++i) {
                    int r = row0 + m*16 + lg*4 + i;
                    float v = fmaxf(acc2[m][n][i] + bias, 0.f);
                    sH2[r * PAD + n*16 + l15] = (unsigned short)f2bf(v);
                }
            }
        }
    }
    __syncthreads();

    // --- GEMM3: O = H2 @ W3 + b3, per wave 32x128, K=64; fused max over the 32 rows ---
    {
        bf16x8 a3[2][2];
        #pragma unroll
        for (int m = 0; m < 2; ++m)
            #pragma unroll
            for (int s = 0; s < 2; ++s)
                a3[m][s] = *(const bf16x8*)&sH2[(row0 + m*16 + l15) * PAD + s*32 + lg*8];

        int q   = q0 + wave;
        int cnt = cnts[q];

        #pragma unroll
        for (int n = 0; n < 8; ++n) {
            bf16x8 b0 = *(const bf16x8*)&sW3T[(n*16 + l15) * PAD +      lg*8];
            bf16x8 b1f= *(const bf16x8*)&sW3T[(n*16 + l15) * PAD + 32 + lg*8];
            f32x4 c0 = {0.f, 0.f, 0.f, 0.f};
            f32x4 c1 = {0.f, 0.f, 0.f, 0.f};
            c0 = __builtin_amdgcn_mfma_f32_16x16x32_bf16(a3[0][0], b0,  c0, 0, 0, 0);
            c0 = __builtin_amdgcn_mfma_f32_16x16x32_bf16(a3[0][1], b1f, c0, 0, 0, 0);
            c1 = __builtin_amdgcn_mfma_f32_16x16x32_bf16(a3[1][0], b0,  c1, 0, 0, 0);
            c1 = __builtin_amdgcn_mfma_f32_16x16x32_bf16(a3[1][1], b1f, c1, 0, 0, 0);

            float bias = b3[n*16 + l15];
            float v = -INFINITY;
            #pragma unroll
            for (int i = 0; i < 4; ++i) {
                int k0 = lg*4 + i;                 // slot of m=0 row
                float t0 = (k0      < cnt) ? c0[i] + bias : -INFINITY;
                float t1 = (k0 + 16 < cnt) ? c1[i] + bias : -INFINITY;
                v = fmaxf(v, fmaxf(t0, t1));
            }
            v = fmaxf(v, __shfl_xor(v, 16));
            v = fmaxf(v, __shfl_xor(v, 32));
            if (lane < 16) out[q*128 + n*16 + lane] = v;
        }
    }
}

// ---------------- tail: copy pos + batch into output tuple ----------------
__global__ void tail_kernel(const float* __restrict__ pos,
                            const int* __restrict__ batch,
                            float* __restrict__ out) {
    int i = blockIdx.x * 256 + threadIdx.x;
    if (i < NTOT*3) out[NTOT*128 + i] = pos[i];
    if (i < NTOT)   out[NTOT*131 + i] = (float)batch[i];
}

extern "C" void kernel_launch(void* const* d_in, const int* in_sizes, int n_in,
                              void* d_out, int out_size, void* d_ws, size_t ws_size,
                              hipStream_t stream) {
    const float* x     = (const float*)d_in[0];
    const float* pos   = (const float*)d_in[1];
    const int*   batch = (const int*)d_in[2];
    const float* W1    = (const float*)d_in[3];
    const float* b1    = (const float*)d_in[4];
    const float* W2    = (const float*)d_in[5];
    const float* b2    = (const float*)d_in[6];
    const float* W3    = (const float*)d_in[7];
    const float* b3    = (const float*)d_in[8];
    float* out = (float*)d_out;

    int* nbr  = (int*)d_ws;                 // [NTOT][32]
    int* cnts = nbr + NTOT * KMAX;          // [NTOT]

    nbr_kernel<<<NTOT * 64 / 256, 256, 0, stream>>>(pos, nbr, cnts);
    mlp_kernel<<<NTOT / 4, 256, 0, stream>>>(x, pos, W1, b1, W2, b2, W3, b3,
                                             nbr, cnts, out);
    tail_kernel<<<(NTOT * 3 + 255) / 256, 256, 0, stream>>>(pos, batch, out);
}

// Round 3
// 86.195 us; speedup vs baseline: 36.5061x; 1.3714x over previous
//
#include <hip/hip_runtime.h>
#include <hip/hip_bf16.h>
#include <math.h>

#define NPC   2048          // points per cloud
#define NC    8             // clouds
#define NTOT  (NPC * NC)    // 16384
#define KMAX  32
#define R2    0.04f         // f32(0.04) — boundary-exact vs numpy's f64 compare
#define PAD   72            // sH2 row stride in shorts (144B) -> low-order bank aliasing only

typedef short bf16x8 __attribute__((ext_vector_type(8)));
typedef float f32x4  __attribute__((ext_vector_type(4)));

__device__ __forceinline__ float4 ld4(const float* p) {
    return *reinterpret_cast<const float4*>(p);
}

// f32 -> bf16 round-to-nearest-even (finite values only)
__device__ __forceinline__ unsigned int f2bf(float f) {
    unsigned int u = __float_as_uint(f);
    return (u + 0x7FFFu + ((u >> 16) & 1u)) >> 16;
}

// ---------------- neighbor search: one wave per query (validated exact) ----------------
__global__ __launch_bounds__(256) void nbr_kernel(const float* __restrict__ pos,
                                                  int* __restrict__ nbr,
                                                  int* __restrict__ cnts) {
    int gid  = blockIdx.x * 256 + threadIdx.x;
    int q    = gid >> 6;
    int lane = threadIdx.x & 63;
    int base = (q >> 11) << 11;
    float qx = pos[3*q], qy = pos[3*q+1], qz = pos[3*q+2];
    int cnt = 0;
    for (int j0 = 0; j0 < NPC && cnt < KMAX; j0 += 64) {
        int j = base + j0 + lane;
        float dx = __fsub_rn(pos[3*j],   qx);
        float dy = __fsub_rn(pos[3*j+1], qy);
        float dz = __fsub_rn(pos[3*j+2], qz);
        float d2 = __fadd_rn(__fadd_rn(__fmul_rn(dx,dx), __fmul_rn(dy,dy)),
                             __fmul_rn(dz,dz));
        bool val = d2 <= R2;
        unsigned long long m = __ballot(val);
        int before = (int)__popcll(m & ((1ull << lane) - 1ull));
        int slot = cnt + before;
        if (val && slot < KMAX) nbr[(q << 5) + slot] = j;
        cnt += (int)__popcll(m);
    }
    if (lane == 0) cnts[q] = cnt < KMAX ? cnt : KMAX;
}

// ---------------- prep (weights -> bf16 B-frag layout in ws) + tail copies ----------------
// B-frag for mfma_16x16x32_bf16: lane holds B[k = (lane>>4)*8 + j][col = lane&15], j=0..7.
// wg2[((n*2+s)*64 + lane)*8 + j] = bf16(W2[(s*32 + (lane>>4)*8 + j)*64  + n*16 + (lane&15)])
// wg3 analogous with W3 row stride 128.
__global__ __launch_bounds__(256) void prep_tail_kernel(const float* __restrict__ pos,
                                                        const int* __restrict__ batch,
                                                        const float* __restrict__ W2,
                                                        const float* __restrict__ W3,
                                                        unsigned short* __restrict__ wg2,
                                                        unsigned short* __restrict__ wg3,
                                                        float* __restrict__ out) {
    int i = blockIdx.x * 256 + threadIdx.x;
    if (i < NTOT*3) out[NTOT*128 + i] = pos[i];
    if (i < NTOT)   out[NTOT*131 + i] = (float)batch[i];
    if (blockIdx.x == 0) {
        int t = threadIdx.x;
        for (int g = t; g < 64*64; g += 256) {
            int j = g & 7, lane = (g >> 3) & 63, ns = g >> 9;
            int n = ns >> 1, s = ns & 1;
            int k = s*32 + (lane >> 4)*8 + j, col = n*16 + (lane & 15);
            wg2[g] = (unsigned short)f2bf(W2[k*64 + col]);
        }
        for (int g = t; g < 64*128; g += 256) {
            int j = g & 7, lane = (g >> 3) & 63, ns = g >> 9;
            int n = ns >> 1, s = ns & 1;
            int k = s*32 + (lane >> 4)*8 + j, col = n*16 + (lane & 15);
            wg3[g] = (unsigned short)f2bf(W3[k*128 + col]);
        }
    }
}

// ---------------- fused MLP (MFMA) + max-aggregation ----------------
// Block: 256 threads = 4 waves; wave w owns query q0+w (32 edge rows). No __syncthreads:
// sH2 slices are wave-private (write+read own 32 rows only).
__global__ __launch_bounds__(256, 4) void mlp_kernel(
    const float* __restrict__ x, const float* __restrict__ pos,
    const float* __restrict__ W1, const float* __restrict__ b1,
    const float* __restrict__ b2, const float* __restrict__ b3,
    const unsigned short* __restrict__ wg2, const unsigned short* __restrict__ wg3,
    const int* __restrict__ nbr, const int* __restrict__ cnts,
    float* __restrict__ out)
{
    __shared__ unsigned short sH2[128 * PAD];   // 18432 B

    const int tid  = threadIdx.x;
    const int wave = tid >> 6, lane = tid & 63;
    const int l15  = lane & 15, lg = lane >> 4;
    const int q    = blockIdx.x * 4 + wave;
    const int cnt  = cnts[q];
    const int row0 = wave * 32;

    // --- layer 1 (VALU), computed directly into MFMA A-fragments ---
    // lane (lg,l15) owns rows {l15, 16+l15} of its wave, channels {lg*8..+7, 32+lg*8..+7}.
    bf16x8 a1f[2][2];
    #pragma unroll
    for (int m = 0; m < 2; ++m) {
        int k  = m*16 + l15;                       // neighbor slot
        int jg = (k < cnt) ? nbr[(q << 5) + k] : q;
        float msg[6];
        msg[0] = x[3*jg]; msg[1] = x[3*jg+1]; msg[2] = x[3*jg+2];
        msg[3] = pos[3*jg]   - pos[3*q];
        msg[4] = pos[3*jg+1] - pos[3*q+1];
        msg[5] = pos[3*jg+2] - pos[3*q+2];
        #pragma unroll
        for (int s = 0; s < 2; ++s) {
            int ch0 = s*32 + lg*8;
            float4 bb0 = ld4(b1 + ch0), bb1 = ld4(b1 + ch0 + 4);
            float h[8] = {bb0.x, bb0.y, bb0.z, bb0.w, bb1.x, bb1.y, bb1.z, bb1.w};
            #pragma unroll
            for (int c = 0; c < 6; ++c) {
                float4 w0 = ld4(W1 + c*64 + ch0), w1 = ld4(W1 + c*64 + ch0 + 4);
                h[0] = fmaf(msg[c], w0.x, h[0]);
                h[1] = fmaf(msg[c], w0.y, h[1]);
                h[2] = fmaf(msg[c], w0.z, h[2]);
                h[3] = fmaf(msg[c], w0.w, h[3]);
                h[4] = fmaf(msg[c], w1.x, h[4]);
                h[5] = fmaf(msg[c], w1.y, h[5]);
                h[6] = fmaf(msg[c], w1.z, h[6]);
                h[7] = fmaf(msg[c], w1.w, h[7]);
            }
            int p0 = (int)(f2bf(fmaxf(h[0],0.f)) | (f2bf(fmaxf(h[1],0.f)) << 16));
            int p1 = (int)(f2bf(fmaxf(h[2],0.f)) | (f2bf(fmaxf(h[3],0.f)) << 16));
            int p2 = (int)(f2bf(fmaxf(h[4],0.f)) | (f2bf(fmaxf(h[5],0.f)) << 16));
            int p3 = (int)(f2bf(fmaxf(h[6],0.f)) | (f2bf(fmaxf(h[7],0.f)) << 16));
            int4 pk = {p0, p1, p2, p3};
            a1f[m][s] = __builtin_bit_cast(bf16x8, pk);
        }
    }

    // --- GEMM2: H2 = relu(H1 @ W2 + b2), per-wave 32x64, K=64; B-frags from global ---
    {
        f32x4 acc2[2][4] = {};
        #pragma unroll
        for (int n = 0; n < 4; ++n) {
            bf16x8 bf0 = *(const bf16x8*)(wg2 + ((n*2 + 0)*64 + lane)*8);
            bf16x8 bf1 = *(const bf16x8*)(wg2 + ((n*2 + 1)*64 + lane)*8);
            #pragma unroll
            for (int m = 0; m < 2; ++m) {
                acc2[m][n] = __builtin_amdgcn_mfma_f32_16x16x32_bf16(a1f[m][0], bf0, acc2[m][n], 0, 0, 0);
                acc2[m][n] = __builtin_amdgcn_mfma_f32_16x16x32_bf16(a1f[m][1], bf1, acc2[m][n], 0, 0, 0);
            }
        }
        // epilogue: bias + relu + bf16 -> wave-private sH2 rows
        #pragma unroll
        for (int n = 0; n < 4; ++n) {
            float bias = b2[n*16 + l15];
            #pragma unroll
            for (int m = 0; m < 2; ++m) {
                #pragma unroll
                for (int i = 0; i < 4; ++i) {
                    int r = row0 + m*16 + lg*4 + i;
                    float v = fmaxf(acc2[m][n][i] + bias, 0.f);
                    sH2[r * PAD + n*16 + l15] = (unsigned short)f2bf(v);
                }
            }
        }
    }

    __builtin_amdgcn_wave_barrier();   // compile-time order pin (wave-private data; lgkmcnt handles HW)

    // --- GEMM3: O = H2 @ W3 + b3 (32x128, K=64), fused max over the 32 rows ---
    {
        bf16x8 a3[2][2];
        #pragma unroll
        for (int m = 0; m < 2; ++m)
            #pragma unroll
            for (int s = 0; s < 2; ++s)
                a3[m][s] = *(const bf16x8*)&sH2[(row0 + m*16 + l15) * PAD + s*32 + lg*8];

        #pragma unroll
        for (int n = 0; n < 8; ++n) {
            bf16x8 bf0 = *(const bf16x8*)(wg3 + ((n*2 + 0)*64 + lane)*8);
            bf16x8 bf1 = *(const bf16x8*)(wg3 + ((n*2 + 1)*64 + lane)*8);
            f32x4 c0 = {0.f, 0.f, 0.f, 0.f};
            f32x4 c1 = {0.f, 0.f, 0.f, 0.f};
            c0 = __builtin_amdgcn_mfma_f32_16x16x32_bf16(a3[0][0], bf0, c0, 0, 0, 0);
            c0 = __builtin_amdgcn_mfma_f32_16x16x32_bf16(a3[0][1], bf1, c0, 0, 0, 0);
            c1 = __builtin_amdgcn_mfma_f32_16x16x32_bf16(a3[1][0], bf0, c1, 0, 0, 0);
            c1 = __builtin_amdgcn_mfma_f32_16x16x32_bf16(a3[1][1], bf1, c1, 0, 0, 0);

            float bias = b3[n*16 + l15];
            float v = -INFINITY;
            #pragma unroll
            for (int i = 0; i < 4; ++i) {
                int k0 = lg*4 + i;
                float t0 = (k0      < cnt) ? c0[i] + bias : -INFINITY;
                float t1 = (k0 + 16 < cnt) ? c1[i] + bias : -INFINITY;
                v = fmaxf(v, fmaxf(t0, t1));
            }
            v = fmaxf(v, __shfl_xor(v, 16));
            v = fmaxf(v, __shfl_xor(v, 32));
            if (lane < 16) out[q*128 + n*16 + lane] = v;
        }
    }
}

extern "C" void kernel_launch(void* const* d_in, const int* in_sizes, int n_in,
                              void* d_out, int out_size, void* d_ws, size_t ws_size,
                              hipStream_t stream) {
    const float* x     = (const float*)d_in[0];
    const float* pos   = (const float*)d_in[1];
    const int*   batch = (const int*)d_in[2];
    const float* W1    = (const float*)d_in[3];
    const float* b1    = (const float*)d_in[4];
    const float* W2    = (const float*)d_in[5];
    const float* b2    = (const float*)d_in[6];
    const float* W3    = (const float*)d_in[7];
    const float* b3    = (const float*)d_in[8];
    float* out = (float*)d_out;

    int* nbr  = (int*)d_ws;                          // [NTOT][32]
    int* cnts = nbr + NTOT * KMAX;                   // [NTOT]
    unsigned short* wg2 = (unsigned short*)(cnts + NTOT);   // [4096] bf16 frag
    unsigned short* wg3 = wg2 + 64*64;               // [8192] bf16 frag

    prep_tail_kernel<<<(NTOT*3 + 255)/256, 256, 0, stream>>>(pos, batch, W2, W3, wg2, wg3, out);
    nbr_kernel<<<NTOT * 64 / 256, 256, 0, stream>>>(pos, nbr, cnts);
    mlp_kernel<<<NTOT / 4, 256, 0, stream>>>(x, pos, W1, b1, b2, b3, wg2, wg3,
                                             nbr, cnts, out);
}

// Round 5
// 68.489 us; speedup vs baseline: 45.9439x; 1.2585x over previous
//
#include <hip/hip_runtime.h>
#include <hip/hip_bf16.h>
#include <math.h>

#define NPC   2048          // points per cloud
#define NC    8             // clouds
#define NTOT  (NPC * NC)    // 16384
#define KMAX  32
#define R2    0.04f         // f32(0.04) — boundary-exact vs numpy's f64 compare

typedef short bf16x8  __attribute__((ext_vector_type(8)));
typedef float f32x16  __attribute__((ext_vector_type(16)));

__device__ __forceinline__ float4 ld4(const float* p) {
    return *reinterpret_cast<const float4*>(p);
}

// f32 -> bf16 round-to-nearest-even (finite values only)
__device__ __forceinline__ unsigned int f2bf(float f) {
    unsigned int u = __float_as_uint(f);
    return (u + 0x7FFFu + ((u >> 16) & 1u)) >> 16;
}

// packed f32x2 -> bf16x2 (RNE), single instruction
__device__ __forceinline__ unsigned int pkbf(float a, float b) {
    unsigned int r;
    asm("v_cvt_pk_bf16_f32 %0, %1, %2" : "=v"(r) : "v"(a), "v"(b));
    return r;
}

// ============ kernel 1: neighbor search (blocks 0..4095) + xp pack + weight frags + tail ============
__global__ __launch_bounds__(256) void nbr_aux_kernel(
    const float* __restrict__ x, const float* __restrict__ pos,
    const int* __restrict__ batch,
    const float* __restrict__ W2, const float* __restrict__ W3,
    int* __restrict__ nbr, int* __restrict__ cnts,
    float* __restrict__ xp, unsigned short* __restrict__ wg2a,
    unsigned short* __restrict__ wg3b, float* __restrict__ out)
{
    int b = blockIdx.x, tid = threadIdx.x;
    if (b < 4096) {
        // ---- radius query: one wave per query, first-32 in index order (validated exact) ----
        int q    = b * 4 + (tid >> 6);
        int lane = tid & 63;
        int base = (q >> 11) << 11;
        float qx = pos[3*q], qy = pos[3*q+1], qz = pos[3*q+2];
        int cnt = 0;
        for (int j0 = 0; j0 < NPC && cnt < KMAX; j0 += 64) {
            int j = base + j0 + lane;
            float dx = __fsub_rn(pos[3*j],   qx);
            float dy = __fsub_rn(pos[3*j+1], qy);
            float dz = __fsub_rn(pos[3*j+2], qz);
            float d2 = __fadd_rn(__fadd_rn(__fmul_rn(dx,dx), __fmul_rn(dy,dy)),
                                 __fmul_rn(dz,dz));
            bool val = d2 <= R2;
            unsigned long long m = __ballot(val);
            int before = (int)__popcll(m & ((1ull << lane) - 1ull));
            int slot = cnt + before;
            if (val && slot < KMAX) nbr[(q << 5) + slot] = j;
            cnt += (int)__popcll(m);
        }
        if (lane == 0) cnts[q] = cnt < KMAX ? cnt : KMAX;
    } else if (b < 4160) {
        // ---- xp pack: {x0,x1,x2,p0,p1,p2,0,0} per point (32B records) ----
        int i = (b - 4096) * 256 + tid;
        float4 v0 = {x[3*i], x[3*i+1], x[3*i+2], pos[3*i]};
        float4 v1 = {pos[3*i+1], pos[3*i+2], 0.f, 0.f};
        float4* dst = (float4*)(xp + 8 * i);
        dst[0] = v0; dst[1] = v1;
    } else if (b < 4208) {
        // ---- weight fragments for 32x32x16 MFMA (12288 threads = 48 blocks) ----
        // A-frag(W2^T): lane holds A[row=t*32+(lane&31)][k=kk*16+(lane>>5)*8+j]
        // B-frag(W3):   lane holds B[k=kk*16+(lane>>5)*8+j][col=n*32+(lane&31)]
        int g = (b - 4160) * 256 + tid;       // 0..12287
        if (g < 4096) {
            int j = g & 7, lane = (g >> 3) & 63, tk = g >> 9;
            int t = tk >> 2, kk = tk & 3;
            wg2a[g] = (unsigned short)f2bf(W2[(kk*16 + (lane>>5)*8 + j)*64 + t*32 + (lane&31)]);
        } else {
            int g2 = g - 4096;                // 0..8191
            int j = g2 & 7, lane = (g2 >> 3) & 63, nk = g2 >> 9;
            int n = nk >> 2, kk = nk & 3;
            wg3b[g2] = (unsigned short)f2bf(W3[(kk*16 + (lane>>5)*8 + j)*128 + n*32 + (lane&31)]);
        }
    } else {
        // ---- tail copies: pos + batch into output tuple ----
        int i = (b - 4208) * 256 + tid;
        if (i < NTOT*3) out[NTOT*128 + i] = pos[i];
        if (i < NTOT)   out[NTOT*131 + i] = (float)batch[i];
    }
}

// ============ kernel 2: fused MLP (32x32x16 MFMA, LDS-free) + max-aggregation ============
// 4 waves/block, one query per wave; lane owns edge e = lane&31, hi = lane>>5.
__global__ __launch_bounds__(256, 4) void mlp_kernel(
    const float* __restrict__ W1, const float* __restrict__ b1,
    const float* __restrict__ b2, const float* __restrict__ b3,
    const unsigned short* __restrict__ wg2a, const unsigned short* __restrict__ wg3b,
    const float* __restrict__ xp,
    const int* __restrict__ nbr, const int* __restrict__ cnts,
    float* __restrict__ out)
{
    const int tid  = threadIdx.x;
    const int lane = tid & 63;
    const int e    = lane & 31, hi = lane >> 5;
    const int qq   = __builtin_amdgcn_readfirstlane(blockIdx.x * 4 + (tid >> 6));
    const int cnt  = cnts[qq];

    // ---- gather msg (one edge per lane, packed 32B record) ----
    int jg = (e < cnt) ? nbr[(qq << 5) + e] : qq;
    const float4* xpj = (const float4*)(xp + 8 * jg);
    float4 xj0 = xpj[0], xj1 = xpj[1];
    const float4* xpq = (const float4*)(xp + 8 * qq);
    float4 xq0 = xpq[0], xq1 = xpq[1];
    float msg[6];
    msg[0] = xj0.x; msg[1] = xj0.y; msg[2] = xj0.z;
    msg[3] = xj0.w - xq0.w;
    msg[4] = xj1.x - xq1.x;
    msg[5] = xj1.y - xq1.y;

    // ---- layer 1 (VALU) directly into GEMM2 B-frags: ch = kk*16 + hi*8 + j ----
    bf16x8 b1f[4];
    #pragma unroll
    for (int kk = 0; kk < 4; ++kk) {
        int ch0 = kk*16 + hi*8;
        float4 bb0 = ld4(b1 + ch0), bb1 = ld4(b1 + ch0 + 4);
        float h[8] = {bb0.x, bb0.y, bb0.z, bb0.w, bb1.x, bb1.y, bb1.z, bb1.w};
        #pragma unroll
        for (int c = 0; c < 6; ++c) {
            float4 w0 = ld4(W1 + c*64 + ch0), w1 = ld4(W1 + c*64 + ch0 + 4);
            h[0] = fmaf(msg[c], w0.x, h[0]);
            h[1] = fmaf(msg[c], w0.y, h[1]);
            h[2] = fmaf(msg[c], w0.z, h[2]);
            h[3] = fmaf(msg[c], w0.w, h[3]);
            h[4] = fmaf(msg[c], w1.x, h[4]);
            h[5] = fmaf(msg[c], w1.y, h[5]);
            h[6] = fmaf(msg[c], w1.z, h[6]);
            h[7] = fmaf(msg[c], w1.w, h[7]);
        }
        int4 w;
        w.x = (int)pkbf(fmaxf(h[0],0.f), fmaxf(h[1],0.f));
        w.y = (int)pkbf(fmaxf(h[2],0.f), fmaxf(h[3],0.f));
        w.z = (int)pkbf(fmaxf(h[4],0.f), fmaxf(h[5],0.f));
        w.w = (int)pkbf(fmaxf(h[6],0.f), fmaxf(h[7],0.f));
        b1f[kk] = __builtin_bit_cast(bf16x8, w);
    }

    // ---- GEMM2 (swapped): C2^T[64 out][32 edges] = W2^T @ H1^T ----
    f32x16 acc0 = {}, acc1 = {};
    #pragma unroll
    for (int kk = 0; kk < 4; ++kk) {
        bf16x8 a0 = *(const bf16x8*)(wg2a + ((0*4 + kk)*64 + lane)*8);
        bf16x8 a1 = *(const bf16x8*)(wg2a + ((1*4 + kk)*64 + lane)*8);
        acc0 = __builtin_amdgcn_mfma_f32_32x32x16_bf16(a0, b1f[kk], acc0, 0, 0, 0);
        acc1 = __builtin_amdgcn_mfma_f32_32x32x16_bf16(a1, b1f[kk], acc1, 0, 0, 0);
    }

    // ---- epilogue2: bias+relu -> bf16 pairs; half-swap assembles GEMM3 A-frags in-register ----
    // own channels: t*32 + (reg&3) + 8*(reg>>2) + 4*hi ; pack pairs per (t, g=reg>>2)
    unsigned int w_own[2][4][2];
    #pragma unroll
    for (int t = 0; t < 2; ++t) {
        #pragma unroll
        for (int g = 0; g < 4; ++g) {
            float4 bv = ld4(b2 + t*32 + 8*g + 4*hi);
            float v0, v1, v2, v3;
            if (t == 0) {
                v0 = acc0[4*g+0] + bv.x; v1 = acc0[4*g+1] + bv.y;
                v2 = acc0[4*g+2] + bv.z; v3 = acc0[4*g+3] + bv.w;
            } else {
                v0 = acc1[4*g+0] + bv.x; v1 = acc1[4*g+1] + bv.y;
                v2 = acc1[4*g+2] + bv.z; v3 = acc1[4*g+3] + bv.w;
            }
            w_own[t][g][0] = pkbf(fmaxf(v0,0.f), fmaxf(v1,0.f));
            w_own[t][g][1] = pkbf(fmaxf(v2,0.f), fmaxf(v3,0.f));
        }
    }
    // exchange: hi=0 sends odd-g words, hi=1 sends even-g words (what the partner needs)
    unsigned int R[2][2][2];
    #pragma unroll
    for (int t = 0; t < 2; ++t)
        #pragma unroll
        for (int gg = 0; gg < 2; ++gg)
            #pragma unroll
            for (int u = 0; u < 2; ++u) {
                unsigned int send = hi ? w_own[t][2*gg][u] : w_own[t][2*gg+1][u];
                R[t][gg][u] = (unsigned int)__shfl_xor((int)send, 32);
            }
    // assemble: b2f[kk] = H2[e][ch = kk*16 + hi*8 + j], j=0..7
    bf16x8 b2f[4];
    #pragma unroll
    for (int kk = 0; kk < 4; ++kk) {
        int t = kk >> 1;
        unsigned int O0 = hi ? w_own[t][(2*kk+1)&3][0] : w_own[t][(2*kk)&3][0];
        unsigned int O1 = hi ? w_own[t][(2*kk+1)&3][1] : w_own[t][(2*kk)&3][1];
        unsigned int R0 = R[t][kk&1][0];
        unsigned int R1 = R[t][kk&1][1];
        int4 w;
        w.x = (int)(hi ? R0 : O0);
        w.y = (int)(hi ? R1 : O1);
        w.z = (int)(hi ? O0 : R0);
        w.w = (int)(hi ? O1 : R1);
        b2f[kk] = __builtin_bit_cast(bf16x8, w);
    }

    // ---- GEMM3 (non-swapped): C[32 edges][128 out], rows=edges in regs -> in-reg max ----
    #pragma unroll
    for (int n = 0; n < 4; ++n) {
        f32x16 c = {};
        #pragma unroll
        for (int kk = 0; kk < 4; ++kk) {
            bf16x8 bw = *(const bf16x8*)(wg3b + ((n*4 + kk)*64 + lane)*8);
            c = __builtin_amdgcn_mfma_f32_32x32x16_bf16(b2f[kk], bw, c, 0, 0, 0);
        }
        float bias = b3[n*32 + e];
        float m = -INFINITY;
        #pragma unroll
        for (int reg = 0; reg < 16; ++reg) {
            int r = (reg & 3) + 8*(reg >> 2) + 4*hi;   // edge row
            float v = (r < cnt) ? c[reg] + bias : -INFINITY;
            m = fmaxf(m, v);
        }
        m = fmaxf(m, __shfl_xor(m, 32));
        if (hi == 0) out[qq*128 + n*32 + e] = m;
    }
}

extern "C" void kernel_launch(void* const* d_in, const int* in_sizes, int n_in,
                              void* d_out, int out_size, void* d_ws, size_t ws_size,
                              hipStream_t stream) {
    const float* x     = (const float*)d_in[0];
    const float* pos   = (const float*)d_in[1];
    const int*   batch = (const int*)d_in[2];
    const float* W1    = (const float*)d_in[3];
    const float* b1    = (const float*)d_in[4];
    const float* W2    = (const float*)d_in[5];
    const float* b2    = (const float*)d_in[6];
    const float* W3    = (const float*)d_in[7];
    const float* b3    = (const float*)d_in[8];
    float* out = (float*)d_out;

    int* nbr  = (int*)d_ws;                                  // 16384*32 int   (2 MB)
    int* cnts = nbr + NTOT * KMAX;                           // 16384 int      (64 KB)
    float* xp = (float*)(cnts + NTOT);                       // 16384*8 f32    (512 KB)
    unsigned short* wg2a = (unsigned short*)(xp + NTOT * 8); // 4096 bf16      (8 KB)
    unsigned short* wg3b = wg2a + 64 * 64;                   // 8192 bf16      (16 KB)

    nbr_aux_kernel<<<4400, 256, 0, stream>>>(x, pos, batch, W2, W3,
                                             nbr, cnts, xp, wg2a, wg3b, out);
    mlp_kernel<<<NTOT / 4, 256, 0, stream>>>(W1, b1, b2, b3, wg2a, wg3b, xp,
                                             nbr, cnts, out);
}

// Round 6
// 41.682 us; speedup vs baseline: 75.4910x; 1.6431x over previous
//
#include <hip/hip_runtime.h>
#include <hip/hip_bf16.h>
#include <math.h>

#define NPC   2048          // points per cloud
#define NC    8             // clouds
#define NTOT  (NPC * NC)    // 16384
#define KMAX  32
#define R2    0.04f         // f32(0.04) — boundary-exact vs numpy's f64 compare

typedef short bf16x8  __attribute__((ext_vector_type(8)));
typedef float f32x16  __attribute__((ext_vector_type(16)));

// f32 -> bf16 round-to-nearest-even (finite values only)
__device__ __forceinline__ unsigned int f2bf(float f) {
    unsigned int u = __float_as_uint(f);
    return (u + 0x7FFFu + ((u >> 16) & 1u)) >> 16;
}

// packed f32x2 -> bf16x2 (RNE), src0 in LOW half (validated round 5)
__device__ __forceinline__ unsigned int pkbf(float a, float b) {
    unsigned int r;
    asm("v_cvt_pk_bf16_f32 %0, %1, %2" : "=v"(r) : "v"(a), "v"(b));
    return r;
}

// ---- half-swap epilogue (validated round 5): swapped C^T accum -> relu -> bf16 operand frags ----
// in:  a0/a1 hold C^T[ch = t*32 + (reg&3)+8*(reg>>2)+4*hi][e]   (bias already included)
// out: bout[kk] = relu(C)[e][ch = kk*16 + hi*8 + j]  (usable as A- or B-operand frag)
__device__ __forceinline__ void epi_swap(const f32x16& a0, const f32x16& a1,
                                         int hi, bf16x8 bout[4]) {
    unsigned int w_own[2][4][2];
    #pragma unroll
    for (int g = 0; g < 4; ++g) {
        w_own[0][g][0] = pkbf(fmaxf(a0[4*g+0],0.f), fmaxf(a0[4*g+1],0.f));
        w_own[0][g][1] = pkbf(fmaxf(a0[4*g+2],0.f), fmaxf(a0[4*g+3],0.f));
        w_own[1][g][0] = pkbf(fmaxf(a1[4*g+0],0.f), fmaxf(a1[4*g+1],0.f));
        w_own[1][g][1] = pkbf(fmaxf(a1[4*g+2],0.f), fmaxf(a1[4*g+3],0.f));
    }
    unsigned int R[2][2][2];
    #pragma unroll
    for (int t = 0; t < 2; ++t)
        #pragma unroll
        for (int gg = 0; gg < 2; ++gg)
            #pragma unroll
            for (int u = 0; u < 2; ++u) {
                unsigned int send = hi ? w_own[t][2*gg][u] : w_own[t][2*gg+1][u];
                R[t][gg][u] = (unsigned int)__shfl_xor((int)send, 32);
            }
    #pragma unroll
    for (int kk = 0; kk < 4; ++kk) {
        int t = kk >> 1;
        unsigned int O0 = hi ? w_own[t][(2*kk+1)&3][0] : w_own[t][(2*kk)&3][0];
        unsigned int O1 = hi ? w_own[t][(2*kk+1)&3][1] : w_own[t][(2*kk)&3][1];
        unsigned int R0 = R[t][kk&1][0], R1 = R[t][kk&1][1];
        int4 w;
        w.x = (int)(hi ? R0 : O0);
        w.y = (int)(hi ? R1 : O1);
        w.z = (int)(hi ? O0 : R0);
        w.w = (int)(hi ? O1 : R1);
        bout[kk] = __builtin_bit_cast(bf16x8, w);
    }
}

// ============ kernel 1: nbr search + xp pack + weight frags + tail copies ============
__global__ __launch_bounds__(256) void prep_kernel(
    const float* __restrict__ x, const float* __restrict__ pos,
    const int* __restrict__ batch,
    const float* __restrict__ W1, const float* __restrict__ b1,
    const float* __restrict__ W2, const float* __restrict__ b2,
    const float* __restrict__ W3,
    int* __restrict__ nbr, int* __restrict__ cnts,
    float* __restrict__ xp, unsigned short* __restrict__ wf,
    float* __restrict__ out)
{
    int b = blockIdx.x, tid = threadIdx.x;
    if (b < 4096) {
        // ---- radius query: one wave per query; 256-pt groups, early-exit per group ----
        int q    = b * 4 + (tid >> 6);
        int lane = tid & 63;
        int base = (q >> 11) << 11;
        float qx = pos[3*q], qy = pos[3*q+1], qz = pos[3*q+2];
        int cnt = 0;
        for (int j0 = 0; j0 < NPC && cnt < KMAX; j0 += 256) {
            unsigned long long ms[4];
            bool vs[4];
            #pragma unroll
            for (int s = 0; s < 4; ++s) {
                int j = base + j0 + s*64 + lane;
                float dx = __fsub_rn(pos[3*j],   qx);
                float dy = __fsub_rn(pos[3*j+1], qy);
                float dz = __fsub_rn(pos[3*j+2], qz);
                float d2 = __fadd_rn(__fadd_rn(__fmul_rn(dx,dx), __fmul_rn(dy,dy)),
                                     __fmul_rn(dz,dz));
                vs[s] = d2 <= R2;
                ms[s] = __ballot(vs[s]);
            }
            #pragma unroll
            for (int s = 0; s < 4; ++s) {
                int before = (int)__popcll(ms[s] & ((1ull << lane) - 1ull));
                int slot = cnt + before;
                if (vs[s] && slot < KMAX) nbr[(q << 5) + slot] = base + j0 + s*64 + lane;
                cnt += (int)__popcll(ms[s]);
            }
        }
        if (lane == 0) cnts[q] = cnt < KMAX ? cnt : KMAX;
    } else if (b < 4160) {
        // ---- xp pack: {x0,x1,x2,p0,p1,p2,0,0} per point (32B records) ----
        int i = (b - 4096) * 256 + tid;
        float4 v0 = {x[3*i], x[3*i+1], x[3*i+2], pos[3*i]};
        float4 v1 = {pos[3*i+1], pos[3*i+2], 0.f, 0.f};
        float4* dst = (float4*)(xp + 8 * i);
        dst[0] = v0; dst[1] = v1;
    } else if (b < 4216) {
        // ---- weight fragments, contiguous: wg1a[1024] | wg2a[5120] | wg3b[8192] ushorts ----
        // all frags: lane holds elem[k-part = (lane>>5)*8 + j], tile-col/row = lane&31
        int g = (b - 4160) * 256 + tid;       // 0..14335
        if (g < 1024) {
            // wg1a (layer1 A = W1^T padded K=16, bias at k=6): frag t at g>>9
            int j = g & 7, lane = (g >> 3) & 63, t = g >> 9;
            int k = (lane >> 5)*8 + j, ch = t*32 + (lane & 31);
            float v = (k < 6) ? W1[k*64 + ch] : (k == 6 ? b1[ch] : 0.f);
            wf[g] = (unsigned short)f2bf(v);
        } else if (g < 6144) {
            // wg2a (GEMM2 A = W2^T, K=80 with bias row at k=64): frag f = t*5+kk
            int g2 = g - 1024;
            int j = g2 & 7, lane = (g2 >> 3) & 63, f = g2 >> 9;
            int t = f / 5, kk = f % 5;
            int k = kk*16 + (lane >> 5)*8 + j, row = t*32 + (lane & 31);
            float v = 0.f;
            if (k < 64)       v = W2[k*64 + row];
            else if (k == 64) v = b2[row];
            wf[g] = (unsigned short)f2bf(v);
        } else {
            // wg3b (GEMM3 B = W3, K=64): frag f = n*4+kk
            int g3 = g - 6144;
            int j = g3 & 7, lane = (g3 >> 3) & 63, f = g3 >> 9;
            int n = f >> 2, kk = f & 3;
            int k = kk*16 + (lane >> 5)*8 + j, col = n*32 + (lane & 31);
            wf[g] = (unsigned short)f2bf(W3[k*128 + col]);
        }
    } else {
        // ---- tail copies: pos + batch into output tuple ----
        int i = (b - 4216) * 256 + tid;
        if (i < NTOT*3) out[NTOT*128 + i] = pos[i];
        if (i < NTOT)   out[NTOT*131 + i] = (float)batch[i];
    }
}

// ============ kernel 2: fused MLP, all-MFMA, Q=4 queries per wave ============
__global__ __launch_bounds__(256, 4) void mlp_kernel(
    const unsigned short* __restrict__ wf, const float* __restrict__ b3,
    const float* __restrict__ xp,
    const int* __restrict__ nbr, const int* __restrict__ cnts,
    float* __restrict__ out)
{
    __shared__ int4 sW[1664];   // 26624B: wg2a(640 int4) | wg3b(1024 int4)

    const int tid = threadIdx.x;
    // stage weight frags to LDS once per block
    const int4* wsrc = (const int4*)(wf + 1024);
    #pragma unroll
    for (int it = 0; it < 7; ++it) {
        int idx = it*256 + tid;
        if (idx < 1664) sW[idx] = wsrc[idx];
    }
    const int lane = tid & 63, wave = tid >> 6;
    const int e = lane & 31, hi = lane >> 5;
    // W1 frags live in registers (2 x 16B per lane)
    bf16x8 wf1_0 = *(const bf16x8*)(wf + (0*64 + lane)*8);
    bf16x8 wf1_1 = *(const bf16x8*)(wf + (1*64 + lane)*8);
    __syncthreads();

    const unsigned int one_w = pkbf(1.0f, 0.0f);
    int4 ow = {0,0,0,0};
    if (!hi) ow.x = (int)one_w;
    const bf16x8 onef = __builtin_bit_cast(bf16x8, ow);   // GEMM2 kk=4 B-frag ("1" row)

    // b3 per-lane biases (out-channel = e), loop-invariant
    float b3v0 = b3[0*32 + e], b3v1 = b3[1*32 + e], b3v2 = b3[2*32 + e], b3v3 = b3[3*32 + e];

    const int qbase = __builtin_amdgcn_readfirstlane(blockIdx.x * 16 + wave * 4);

    #pragma unroll 1
    for (int i = 0; i < 4; ++i) {
        const int qq = qbase + i;
        const int cnt = cnts[qq];

        // ---- gather one edge per lane (dup across hi halves) ----
        int jg = (e < cnt) ? nbr[(qq << 5) + e] : qq;
        const float4* pj = (const float4*)(xp + 8*jg);
        float4 xj0 = pj[0], xj1 = pj[1];
        const float4* pq = (const float4*)(xp + 8*qq);
        float4 xq0 = pq[0], xq1 = pq[1];
        float r0 = xj0.w - xq0.w, r1 = xj1.x - xq1.x, r2 = xj1.y - xq1.y;

        // ---- layer1 msg B-frag: k = [x0 x1 x2 r0 r1 r2 1 0 | 0...] ----
        int4 mw;
        mw.x = hi ? 0 : (int)pkbf(xj0.x, xj0.y);
        mw.y = hi ? 0 : (int)pkbf(xj0.z, r0);
        mw.z = hi ? 0 : (int)pkbf(r1, r2);
        mw.w = hi ? 0 : (int)one_w;
        bf16x8 msgf = __builtin_bit_cast(bf16x8, mw);

        // ---- layer1 (swapped): C1^T[64 ch][32 e] = W1p^T @ MSG^T, K=16 ----
        f32x16 acc0 = {}, acc1 = {};
        acc0 = __builtin_amdgcn_mfma_f32_32x32x16_bf16(wf1_0, msgf, acc0, 0, 0, 0);
        acc1 = __builtin_amdgcn_mfma_f32_32x32x16_bf16(wf1_1, msgf, acc1, 0, 0, 0);
        bf16x8 h1f[4];
        epi_swap(acc0, acc1, hi, h1f);

        // ---- GEMM2 (swapped): C2^T[64][32] = W2p^T @ H1^T, K=80 (bias row k=64) ----
        f32x16 c20 = {}, c21 = {};
        #pragma unroll
        for (int kk = 0; kk < 4; ++kk) {
            c20 = __builtin_amdgcn_mfma_f32_32x32x16_bf16(
                    *(const bf16x8*)&sW[(0*5 + kk)*64 + lane], h1f[kk], c20, 0, 0, 0);
            c21 = __builtin_amdgcn_mfma_f32_32x32x16_bf16(
                    *(const bf16x8*)&sW[(1*5 + kk)*64 + lane], h1f[kk], c21, 0, 0, 0);
        }
        c20 = __builtin_amdgcn_mfma_f32_32x32x16_bf16(
                *(const bf16x8*)&sW[(0*5 + 4)*64 + lane], onef, c20, 0, 0, 0);
        c21 = __builtin_amdgcn_mfma_f32_32x32x16_bf16(
                *(const bf16x8*)&sW[(1*5 + 4)*64 + lane], onef, c21, 0, 0, 0);
        bf16x8 h2f[4];
        epi_swap(c20, c21, hi, h2f);

        // ---- GEMM3 (non-swapped): C[32 e][128 out] + fused max over edges ----
        const bool full = (cnt == 32);   // wave-uniform scalar branch
        #pragma unroll
        for (int n = 0; n < 4; ++n) {
            f32x16 c = {};
            #pragma unroll
            for (int kk = 0; kk < 4; ++kk)
                c = __builtin_amdgcn_mfma_f32_32x32x16_bf16(
                        h2f[kk], *(const bf16x8*)&sW[640 + (n*4 + kk)*64 + lane], c, 0, 0, 0);
            float m;
            if (full) {
                m = fmaxf(fmaxf(fmaxf(c[0],c[1]), fmaxf(c[2],c[3])),
                          fmaxf(fmaxf(c[4],c[5]), fmaxf(c[6],c[7])));
                m = fmaxf(m, fmaxf(fmaxf(c[8],c[9]),  fmaxf(c[10],c[11])));
                m = fmaxf(m, fmaxf(fmaxf(c[12],c[13]), fmaxf(c[14],c[15])));
            } else {
                m = -INFINITY;
                #pragma unroll
                for (int reg = 0; reg < 16; ++reg) {
                    int r = (reg & 3) + 8*(reg >> 2) + 4*hi;   // edge slot
                    float v = (r < cnt) ? c[reg] : -INFINITY;
                    m = fmaxf(m, v);
                }
            }
            m = fmaxf(m, __shfl_xor(m, 32));
            m += (n == 0 ? b3v0 : n == 1 ? b3v1 : n == 2 ? b3v2 : b3v3);
            if (hi == 0) out[qq*128 + n*32 + e] = m;
        }
    }
}

extern "C" void kernel_launch(void* const* d_in, const int* in_sizes, int n_in,
                              void* d_out, int out_size, void* d_ws, size_t ws_size,
                              hipStream_t stream) {
    const float* x     = (const float*)d_in[0];
    const float* pos   = (const float*)d_in[1];
    const int*   batch = (const int*)d_in[2];
    const float* W1    = (const float*)d_in[3];
    const float* b1    = (const float*)d_in[4];
    const float* W2    = (const float*)d_in[5];
    const float* b2    = (const float*)d_in[6];
    const float* W3    = (const float*)d_in[7];
    const float* b3    = (const float*)d_in[8];
    float* out = (float*)d_out;

    int* nbr  = (int*)d_ws;                                  // 16384*32 int  (2 MB)
    int* cnts = nbr + NTOT * KMAX;                           // 16384 int     (64 KB)
    float* xp = (float*)(cnts + NTOT);                       // 16384*8 f32   (512 KB)
    unsigned short* wfrag = (unsigned short*)(xp + NTOT*8);  // 14336 bf16    (28 KB)

    prep_kernel<<<4408, 256, 0, stream>>>(x, pos, batch, W1, b1, W2, b2, W3,
                                          nbr, cnts, xp, wfrag, out);
    mlp_kernel<<<NTOT / 16, 256, 0, stream>>>(wfrag, b3, xp, nbr, cnts, out);
}